// Round 13
// baseline (88.168 us; speedup 1.0000x reference)
//
#include <hip/hip_runtime.h>

// Problem constants
#define B_     64
#define L_     1024
#define D_     1280   // 320 float4
#define H1_    640
#define H2_    320
#define NSPLIT 32     // per-batch even-split stripes for pooling
#define KS_    16     // k-splits for mlp1
#define KC_    80     // 1280/16
#define NJT2_  5      // W2 j-tiles of 64

// ---------------- Kernel 1: stripe partials (+ init ctr2 for kernel 3) ----------------
// grid (NSPLIT, B_) x 320 thr. Stripe work BYTE-IDENTICAL to R7-R11 (probe: 25.5us,
// HBM ceiling). s==0 blocks also zero ctr2[b]; consumed by mlp2y two kernel
// launches later -> visibility guaranteed by kernel boundaries, re-inited every
// replay (fixes R12's unknown-init detection bug).
__global__ void pool_partial(const float* __restrict__ rep, const int* __restrict__ blen,
                             float* __restrict__ part, unsigned int* __restrict__ ctr2) {
    const int s   = blockIdx.x;     // stripe
    const int b   = blockIdx.y;     // batch
    const int tid = threadIdx.x;    // 0..319 (float4 lane)

    if (s == 0 && tid == 0) ctr2[b] = 0u;

    const int n  = blen[b] - 2;     // valid rows (>=1)
    const int l0 = 1 + (s * n) / NSPLIT;
    const int l1 = 1 + ((s + 1) * n) / NSPLIT;

    float4 acc = make_float4(0.f, 0.f, 0.f, 0.f);
    const float4* base = (const float4*)rep + (size_t)b * L_ * (D_ / 4) + tid;
    #pragma unroll 8
    for (int l = l0; l < l1; ++l) {
        float4 v = base[(size_t)l * (D_ / 4)];
        acc.x += v.x; acc.y += v.y; acc.z += v.z; acc.w += v.w;
    }
    ((float4*)part)[((size_t)b * NSPLIT + s) * (D_ / 4) + tid] = acc;
}

// ---------------- Kernel 2: non-redundant stripe-reduce + mlp1 ----------------
// grid (KS_, B_) = 1024 blocks x 320 thr. Block (ks,b): reduce its own 80-col
// k-slice of part (10 KB, read exactly once grid-wide — unlike R5's 10x), scale
// by 1/n into LDS, then hpart[ks][b][j] = pl . W1[k-slice, j] for all 640 j.
// W1 read coalesced; 3.3 MB served once from HBM then L3 across 64 b-blocks.
__global__ void reduce_mlp1(const float* __restrict__ part, const int* __restrict__ blen,
                            const float* __restrict__ W1, float* __restrict__ hpart) {
    const int ks  = blockIdx.x;     // 0..15
    const int b   = blockIdx.y;     // 0..63
    const int tid = threadIdx.x;    // 0..319
    const int k0  = ks * KC_;

    __shared__ float ptl[4][KC_];   // partial stripe sums
    __shared__ float pl[KC_];       // pooled k-slice

    // stage: 4 thread-groups x 80 cols, each sums 8 stripes
    {
        const int q = tid / KC_;    // 0..3
        const int c = tid - q * KC_;
        const float* p = part + ((size_t)b * NSPLIT + q * 8) * D_ + k0 + c;
        float s = 0.f;
        #pragma unroll
        for (int ss = 0; ss < 8; ++ss)
            s += p[(size_t)ss * D_];
        ptl[q][c] = s;
    }
    __syncthreads();
    if (tid < KC_) {
        int n = blen[b] - 2; if (n < 1) n = 1;
        pl[tid] = (ptl[0][tid] + ptl[1][tid] + ptl[2][tid] + ptl[3][tid]) / (float)n;
    }
    __syncthreads();

    // compute: 5 wave-groups cover 640 j; thread owns j1, j2 = g*128 + jl (+64)
    const int jl = tid & 63;
    const int g  = tid >> 6;        // 0..4
    const int j1 = g * 128 + jl;
    const int j2 = j1 + 64;

    float a1x = 0.f, a1y = 0.f, a2x = 0.f, a2y = 0.f;
    for (int kk = 0; kk < KC_; kk += 4) {
        const float4 pv = *(const float4*)&pl[kk];           // LDS broadcast
        const float* w = W1 + (size_t)(k0 + kk) * H1_;
        a1x = fmaf(pv.x, w[j1],            a1x);
        a1y = fmaf(pv.y, w[H1_ + j1],      a1y);
        a1x = fmaf(pv.z, w[2 * H1_ + j1],  a1x);
        a1y = fmaf(pv.w, w[3 * H1_ + j1],  a1y);
        a2x = fmaf(pv.x, w[j2],            a2x);
        a2y = fmaf(pv.y, w[H1_ + j2],      a2y);
        a2x = fmaf(pv.z, w[2 * H1_ + j2],  a2x);
        a2y = fmaf(pv.w, w[3 * H1_ + j2],  a2y);
    }
    float* hp = hpart + ((size_t)ks * B_ + b) * H1_;
    hp[j1] = a1x + a1y;
    hp[j2] = a2x + a2y;
}

// ---------------- Kernel 3: h-reduce + emb + last-block y ----------------
// grid (NJT2_, B_) = 320 blocks x 512 thr. ctr2 init'd to 0 by kernel 1, so the
// 5th arrival for batch b has old == 4 EXACTLY (R12's bug fixed). R6 validated
// the fence+atomic cross-XCD pattern on this hardware.
__global__ void mlp2y(const float* __restrict__ hpart, const float* __restrict__ b1,
                      const float* __restrict__ W2, const float* __restrict__ b2,
                      const float* __restrict__ W3, const float* __restrict__ b3,
                      float* __restrict__ out, unsigned int* __restrict__ ctr2) {
    const int jt  = blockIdx.x;     // 0..4
    const int b   = blockIdx.y;     // 0..63
    const int tid = threadIdx.x;    // 0..511
    const int jl  = tid & 63;
    const int kq  = tid >> 6;       // 0..7
    const int j   = jt * 64 + jl;

    __shared__ float hrow[H1_];     // 2.56 KB
    __shared__ float pt[8][64];     // 2 KB

    for (int jj = tid; jj < H1_; jj += 512) {
        float s = b1[jj];
        #pragma unroll
        for (int ks = 0; ks < KS_; ++ks)
            s += hpart[((size_t)ks * B_ + b) * H1_ + jj];
        hrow[jj] = fmaxf(s, 0.f);
    }
    __syncthreads();

    // emb partial over k in [kq*80, kq*80+80)
    float a0 = 0.f, a1 = 0.f, a2 = 0.f, a3 = 0.f;
    const int kbeg = kq * (H1_ / 8);
    const float* w = W2 + (size_t)kbeg * H2_ + j;
    #pragma unroll 5
    for (int k = 0; k < H1_ / 8; k += 4) {
        const float4 hv = *(const float4*)&hrow[kbeg + k];   // wave-uniform broadcast
        a0 = fmaf(hv.x, w[(size_t)(k + 0) * H2_], a0);
        a1 = fmaf(hv.y, w[(size_t)(k + 1) * H2_], a1);
        a2 = fmaf(hv.z, w[(size_t)(k + 2) * H2_], a2);
        a3 = fmaf(hv.w, w[(size_t)(k + 3) * H2_], a3);
    }
    pt[kq][jl] = (a0 + a1) + (a2 + a3);
    __syncthreads();

    if (tid < 64) {
        float e = b2[j];
        #pragma unroll
        for (int q = 0; q < 8; ++q) e += pt[q][jl];
        out[128 + (size_t)b * H2_ + j] = fmaxf(e, 0.f);
    }

    // ---- arrival count (release) ----
    __threadfence();                   // make my emb writes device-visible
    __syncthreads();
    __shared__ unsigned int lastf;
    if (tid == 0) {
        unsigned int old = atomicAdd(&ctr2[b], 1u);
        lastf = (old == (unsigned)(NJT2_ - 1)) ? 1u : 0u;   // init==0 -> exact
    }
    __syncthreads();

    // ---- last block for this batch: y = emb @ W3 + b3 (one wave) ----
    if (lastf && tid < 64) {
        __threadfence();               // acquire other blocks' emb writes
        const int lane = tid;
        float s0 = 0.f, s1 = 0.f;
        #pragma unroll
        for (int i = 0; i < H2_ / 64; ++i) {
            const int jj = lane + i * 64;
            const float e = out[128 + (size_t)b * H2_ + jj];
            s0 = fmaf(e, W3[(size_t)jj * 2 + 0], s0);
            s1 = fmaf(e, W3[(size_t)jj * 2 + 1], s1);
        }
        #pragma unroll
        for (int off = 32; off >= 1; off >>= 1) {
            s0 += __shfl_xor(s0, off, 64);
            s1 += __shfl_xor(s1, off, 64);
        }
        if (lane == 0) {
            out[(size_t)b * 2 + 0] = s0 + b3[0];
            out[(size_t)b * 2 + 1] = s1 + b3[1];
        }
    }
}

extern "C" void kernel_launch(void* const* d_in, const int* in_sizes, int n_in,
                              void* d_out, int out_size, void* d_ws, size_t ws_size,
                              hipStream_t stream) {
    const float* rep  = (const float*)d_in[0];
    const int*   blen = (const int*)  d_in[1];
    const float* W1   = (const float*)d_in[2];
    const float* b1   = (const float*)d_in[3];
    const float* W2   = (const float*)d_in[4];
    const float* b2   = (const float*)d_in[5];
    const float* W3   = (const float*)d_in[6];
    const float* b3   = (const float*)d_in[7];
    float* out = (float*)d_out;

    // workspace layout (floats):
    //   part   B_*NSPLIT*D_ = 2,621,440  (10.5 MB)
    //   hpart  KS_*B_*H1_   =   655,360  (2.62 MB)
    //   ctr2   B_ uints
    float*        ws    = (float*)d_ws;
    float*        part  = ws;
    float*        hpart = part + (size_t)B_ * NSPLIT * D_;
    unsigned int* ctr2  = (unsigned int*)(hpart + (size_t)KS_ * B_ * H1_);

    pool_partial<<<dim3(NSPLIT, B_), 320, 0, stream>>>(rep, blen, part, ctr2);
    reduce_mlp1 <<<dim3(KS_, B_), 320, 0, stream>>>(part, blen, W1, hpart);
    mlp2y       <<<dim3(NJT2_, B_), 512, 0, stream>>>(hpart, b1, W2, b2, W3, b3, out, ctr2);
}